// Round 5
// baseline (135.106 us; speedup 1.0000x reference)
//
#include <hip/hip_runtime.h>
#include <hip/hip_bf16.h>

// Problem constants (B,S,H,Q,D,C) = (8,512,768,64,256,2)
#define B_ 8
#define S_ 512
#define H_ 768
#define Q_ 64
#define D_ 256
#define EPSF 1e-8f

// ============================================================================
// K1: one block per (b, h-chunk of 64). 512 threads (8 waves).
//  A0: load indices, ballots (alen/blen)
//  A1: 64 q-row inverse norms (wave-per-row, 8 rows/wave)
//  A2: qbar[768] (masked normalized sum) + qa chunk (query_avg slice)
//  B : 256 doc dots  w[d] = mask*(qbar.f_d)/(||f_d||*alen*blen)  (qbar in regs)
//  C : qbd chunk = sum_d w[d]*f_d[hchunk]
//  D : partial GEMV: W1 k-rows {hc*64..+64} x (qa) + {768+hc*64..+64} x (qbd)
//      -> partial[(hc*8+b)*768 + 0..767]   (plain stores, no atomics)
// ============================================================================
__global__ __launch_bounds__(512) void k_main(
        const float* __restrict__ feats,
        const int* __restrict__ aidx,
        const int* __restrict__ bidx,
        const float* __restrict__ W1,
        float* __restrict__ partial) {
    const int b = blockIdx.x / 12, hc = blockIdx.x % 12;
    const int t = threadIdx.x, wv = t >> 6, lane = t & 63;

    __shared__ __align__(16) float s_qbar[H_];
    __shared__ float s_k[128];          // [0:64]=qa chunk, [64:128]=qbd chunk
    __shared__ float s_w[D_];
    __shared__ float s_inv[Q_], s_m[Q_];
    __shared__ int   s_ai[Q_], s_bi[D_];
    __shared__ float red[8][64];
    __shared__ int   s_cnt[4];
    __shared__ float s_alen;

    // ---- A0: stage indices ----
    if (t < Q_) s_ai[t] = aidx[b * Q_ + t];
    if (t >= 256) s_bi[t - 256] = bidx[b * D_ + (t - 256)];
    __syncthreads();

    if (wv == 0) {
        unsigned long long ma = __ballot(s_ai[lane] > 0);
        if (lane == 0) s_alen = (float)__popcll(ma);
    } else if (wv >= 4) {
        unsigned long long mb = __ballot(s_bi[(wv - 4) * 64 + lane] > 0);
        if (lane == 0) s_cnt[wv - 4] = __popcll(mb);
    }

    // ---- A1: q-row norms (wave wv owns rows wv*8 .. wv*8+7) ----
    for (int j = 0; j < 8; ++j) {
        int q = wv * 8 + j;
        int idx = s_ai[q];
        const float4* row4 = (const float4*)(feats + (size_t)(b * S_ + idx) * H_);
        float4 v0 = row4[lane], v1 = row4[lane + 64], v2 = row4[lane + 128];
        float ss = v0.x*v0.x + v0.y*v0.y + v0.z*v0.z + v0.w*v0.w
                 + v1.x*v1.x + v1.y*v1.y + v1.z*v1.z + v1.w*v1.w
                 + v2.x*v2.x + v2.y*v2.y + v2.z*v2.z + v2.w*v2.w;
        for (int off = 32; off; off >>= 1) ss += __shfl_xor(ss, off, 64);
        if (lane == 0) {
            float inv = 1.f / fmaxf(sqrtf(ss), EPSF);
            s_inv[q] = (idx > 0) ? inv : 0.f;
            s_m[q]   = (idx > 0) ? 1.f : 0.f;
        }
    }
    __syncthreads();

    // ---- A2: qbar columns (thread t owns h=t, and h=512+t if t<256) ----
    {
        float accb0 = 0.f, acca0 = 0.f, accb1 = 0.f, acca1 = 0.f;
#pragma unroll 8
        for (int q = 0; q < Q_; ++q) {
            const float* row = feats + (size_t)(b * S_ + s_ai[q]) * H_;
            float iv = s_inv[q], mv = s_m[q];
            float f0 = row[t];
            accb0 += f0 * iv; acca0 += f0 * mv;
            if (t < 256) {
                float f1 = row[512 + t];
                accb1 += f1 * iv; acca1 += f1 * mv;
            }
        }
        s_qbar[t] = accb0;
        if (t < 256) s_qbar[512 + t] = accb1;
        int c0 = t - hc * 64;
        if (c0 >= 0 && c0 < 64) s_k[c0] = acca0 / s_alen;
        if (t < 256) {
            int c1 = 512 + t - hc * 64;
            if (c1 >= 0 && c1 < 64) s_k[c1] = acca1 / s_alen;
        }
    }
    __syncthreads();

    // ---- B: doc weights (qbar cached in registers; wave wv owns 32 d's) ----
    {
        const float4* q4 = (const float4*)s_qbar;
        float4 qb0 = q4[lane], qb1 = q4[lane + 64], qb2 = q4[lane + 128];
        float blen = (float)(s_cnt[0] + s_cnt[1] + s_cnt[2] + s_cnt[3]);
        float scale = 1.f / (s_alen * blen);
#pragma unroll 2
        for (int j = 0; j < 32; ++j) {
            int d = wv * 32 + j;
            int idx = s_bi[d];
            const float4* row4 = (const float4*)(feats + (size_t)(b * S_ + idx) * H_);
            float4 v0 = row4[lane], v1 = row4[lane + 64], v2 = row4[lane + 128];
            float dqf = v0.x*qb0.x + v0.y*qb0.y + v0.z*qb0.z + v0.w*qb0.w
                      + v1.x*qb1.x + v1.y*qb1.y + v1.z*qb1.z + v1.w*qb1.w
                      + v2.x*qb2.x + v2.y*qb2.y + v2.z*qb2.z + v2.w*qb2.w;
            float dff = v0.x*v0.x + v0.y*v0.y + v0.z*v0.z + v0.w*v0.w
                      + v1.x*v1.x + v1.y*v1.y + v1.z*v1.z + v1.w*v1.w
                      + v2.x*v2.x + v2.y*v2.y + v2.z*v2.z + v2.w*v2.w;
            for (int off = 32; off; off >>= 1) {
                dqf += __shfl_xor(dqf, off, 64);
                dff += __shfl_xor(dff, off, 64);
            }
            if (lane == 0) {
                float invd = 1.f / fmaxf(sqrtf(dff), EPSF);
                s_w[d] = (idx > 0) ? dqf * invd * scale : 0.f;
            }
        }
    }
    __syncthreads();

    // ---- C: qbd chunk (wave wv sums its 32 d's on columns hc*64+lane) ----
    {
        float acc = 0.f;
#pragma unroll 4
        for (int j = 0; j < 32; ++j) {
            int d = wv * 32 + j;
            acc += s_w[d] * feats[(size_t)(b * S_ + s_bi[d]) * H_ + hc * 64 + lane];
        }
        red[wv][lane] = acc;
    }
    __syncthreads();
    if (t < 64) {
        float q = 0.f;
#pragma unroll
        for (int w8 = 0; w8 < 8; ++w8) q += red[w8][t];
        s_k[64 + t] = q;
    }
    __syncthreads();

    // ---- D: partial GEMV over 128 k-rows -> 768 outputs ----
    {
        const float* Wtop = W1 + (size_t)(hc * 64) * H_;
        const float* Wbot = W1 + (size_t)(H_ + hc * 64) * H_;
        float acc0 = 0.f, acc1 = 0.f;
#pragma unroll 4
        for (int i = 0; i < 64; ++i) {
            float ka = s_k[i], kb = s_k[64 + i];
            const float* r1 = Wtop + (size_t)i * H_;
            const float* r2 = Wbot + (size_t)i * H_;
            acc0 += ka * r1[t] + kb * r2[t];
            if (t < 256) acc1 += ka * r1[512 + t] + kb * r2[512 + t];
        }
        float* po = partial + (size_t)(hc * B_ + b) * H_;
        po[t] = acc0;
        if (t < 256) po[512 + t] = acc1;
    }
}

// ============================================================================
// K2: tail — hidden[b][h] = relu(sum_hc partial + b1); logits = hidden @ W2 + b2
// grid: 8 blocks x 256 threads
// ============================================================================
__global__ __launch_bounds__(256) void k_tail(
        const float* __restrict__ partial,
        const float* __restrict__ b1,
        const float* __restrict__ W2,
        const float* __restrict__ b2,
        float* __restrict__ out) {
    int b = blockIdx.x, t = threadIdx.x, lane = t & 63, wv = t >> 6;
    float a0 = b1[t], a1 = b1[t + 256], a2 = b1[t + 512];
#pragma unroll
    for (int hc = 0; hc < 12; ++hc) {
        const float* p = partial + (size_t)(hc * B_ + b) * H_;
        a0 += p[t]; a1 += p[t + 256]; a2 += p[t + 512];
    }
    a0 = fmaxf(a0, 0.f); a1 = fmaxf(a1, 0.f); a2 = fmaxf(a2, 0.f);
    const float2* W22 = (const float2*)W2;
    float2 w0 = W22[t], w1 = W22[t + 256], w2 = W22[t + 512];
    float p0 = a0 * w0.x + a1 * w1.x + a2 * w2.x;
    float p1 = a0 * w0.y + a1 * w1.y + a2 * w2.y;
    for (int off = 32; off; off >>= 1) {
        p0 += __shfl_xor(p0, off, 64);
        p1 += __shfl_xor(p1, off, 64);
    }
    __shared__ float r0[4], r1[4];
    if (lane == 0) { r0[wv] = p0; r1[wv] = p1; }
    __syncthreads();
    if (t == 0) {
        out[b * 2 + 0] = r0[0] + r0[1] + r0[2] + r0[3] + b2[0];
        out[b * 2 + 1] = r1[0] + r1[1] + r1[2] + r1[3] + b2[1];
    }
}

extern "C" void kernel_launch(void* const* d_in, const int* in_sizes, int n_in,
                              void* d_out, int out_size, void* d_ws, size_t ws_size,
                              hipStream_t stream) {
    const float* feats = (const float*)d_in[0];
    const int*   aidx  = (const int*)d_in[1];
    const int*   bidx  = (const int*)d_in[2];
    const float* W1    = (const float*)d_in[3];
    const float* b1    = (const float*)d_in[4];
    const float* W2    = (const float*)d_in[5];
    const float* b2    = (const float*)d_in[6];
    float* out = (float*)d_out;

    float* partial = (float*)d_ws;   // [12][8][768] floats = 294912 B

    k_main<<<96, 512, 0, stream>>>(feats, aidx, bidx, W1, partial);
    k_tail<<<8, 256, 0, stream>>>(partial, b1, W2, b2, out);
}

// Round 6
// 102.933 us; speedup vs baseline: 1.3126x; 1.3126x over previous
//
#include <hip/hip_runtime.h>
#include <hip/hip_bf16.h>

// Problem constants (B,S,H,Q,D,C) = (8,512,768,64,256,2)
#define B_ 8
#define S_ 512
#define H_ 768
#define Q_ 64
#define D_ 256
#define EPSF 1e-8f

// ws layout (floats)
#define WS_INVD   0                         // [B*D]        2048 (0 if masked)
#define WS_QBARP  (B_ * D_)                 // [2][B][H]   12288
#define WS_QAP    (WS_QBARP + 2 * B_ * H_)  // [2][B][H]   12288 (masked sums, undivided)
#define WS_W      (WS_QAP + 2 * B_ * H_)    // [B*D]        2048
#define WS_HIDDEN (WS_W + B_ * D_)          // [B*H]        6144
#define WS_CNT    (WS_HIDDEN + B_ * H_)     // counter + pad (256)

// ============================================================================
// K1: 256 blocks x 512 threads.
//   blocks 0..191  : (b, hc, qg) — 32 q-row norms (wave-per-4-rows) then
//                    qbar/qa partial sums for 64 h-cols -> qbar_part/qa_part
//   blocks 192..255: masked inverse norms for all 2048 doc rows (4 rows/wave)
// ============================================================================
__global__ __launch_bounds__(512) void k_pre(
        const float* __restrict__ feats,
        const int* __restrict__ aidx,
        const int* __restrict__ bidx,
        float* __restrict__ ws) {
    float* invd      = ws + WS_INVD;
    float* qbar_part = ws + WS_QBARP;
    float* qa_part   = ws + WS_QAP;
    const int t = threadIdx.x, wv = t >> 6, lane = t & 63;

    if (blockIdx.x < 192) {
        const int b = blockIdx.x / 24, rem = blockIdx.x % 24;
        const int hc = rem >> 1, qg = rem & 1;
        __shared__ int   s_ai[32];
        __shared__ float s_inv[32], s_m[32];
        __shared__ float red0[8][64], red1[8][64];
        if (t < 32) s_ai[t] = aidx[b * Q_ + qg * 32 + t];
        __syncthreads();
        // 32 q-row norms: wave wv owns rows wv*4 .. wv*4+3
#pragma unroll
        for (int j = 0; j < 4; ++j) {
            int q = wv * 4 + j;
            int idx = s_ai[q];
            const float4* row4 = (const float4*)(feats + (size_t)(b * S_ + idx) * H_);
            float4 v0 = row4[lane], v1 = row4[lane + 64], v2 = row4[lane + 128];
            float ss = v0.x*v0.x + v0.y*v0.y + v0.z*v0.z + v0.w*v0.w
                     + v1.x*v1.x + v1.y*v1.y + v1.z*v1.z + v1.w*v1.w
                     + v2.x*v2.x + v2.y*v2.y + v2.z*v2.z + v2.w*v2.w;
            for (int off = 32; off; off >>= 1) ss += __shfl_xor(ss, off, 64);
            if (lane == 0) {
                float inv = 1.f / fmaxf(sqrtf(ss), EPSF);
                s_inv[q] = (idx > 0) ? inv : 0.f;
                s_m[q]   = (idx > 0) ? 1.f : 0.f;
            }
        }
        __syncthreads();
        // partial qbar/qa for cols hc*64+lane over this block's 32 q-rows
        int h = hc * 64 + lane;
        float pb = 0.f, pa = 0.f;
#pragma unroll
        for (int j = 0; j < 4; ++j) {
            int q = wv * 4 + j;
            const float* row = feats + (size_t)(b * S_ + s_ai[q]) * H_;
            float f = row[h];
            pb += f * s_inv[q];
            pa += f * s_m[q];
        }
        red0[wv][lane] = pb;
        red1[wv][lane] = pa;
        __syncthreads();
        if (t < 64) {
            float sb = 0.f, sa = 0.f;
#pragma unroll
            for (int k = 0; k < 8; ++k) { sb += red0[k][t]; sa += red1[k][t]; }
            qbar_part[(size_t)(qg * B_ + b) * H_ + hc * 64 + t] = sb;
            qa_part[(size_t)(qg * B_ + b) * H_ + hc * 64 + t]   = sa;
        }
    } else {
        // doc inverse norms (masked): 64 blocks x 8 waves, 4 docs/wave
        int gw = (blockIdx.x - 192) * 8 + wv;        // 0..511
#pragma unroll
        for (int j = 0; j < 4; ++j) {
            int g = gw * 4 + j;                      // 0..2047
            int b = g >> 8, d = g & 255;
            int idx = bidx[b * D_ + d];
            const float4* row4 = (const float4*)(feats + (size_t)(b * S_ + idx) * H_);
            float4 v0 = row4[lane], v1 = row4[lane + 64], v2 = row4[lane + 128];
            float ss = v0.x*v0.x + v0.y*v0.y + v0.z*v0.z + v0.w*v0.w
                     + v1.x*v1.x + v1.y*v1.y + v1.z*v1.z + v1.w*v1.w
                     + v2.x*v2.x + v2.y*v2.y + v2.z*v2.z + v2.w*v2.w;
            for (int off = 32; off; off >>= 1) ss += __shfl_xor(ss, off, 64);
            if (lane == 0)
                invd[b * D_ + d] = (idx > 0) ? 1.f / fmaxf(sqrtf(ss), EPSF) : 0.f;
        }
    }
}

// ============================================================================
// K2: 512 blocks x 256 threads — w[b,d] = invd * dot(qbar, f_d) / (alen*blen)
//     (qbar = sum of 2 parts, read as float4). Blocks 0..24 zero hidden+cnt.
// ============================================================================
__global__ __launch_bounds__(256) void k_docw(
        const float* __restrict__ feats,
        const int* __restrict__ aidx,
        const int* __restrict__ bidx,
        float* __restrict__ ws) {
    const float* invd      = ws + WS_INVD;
    const float* qbar_part = ws + WS_QBARP;
    float* w               = ws + WS_W;
    float* zero_region     = ws + WS_HIDDEN;
    const int t = threadIdx.x, wv = t >> 6, lane = t & 63;
    if (blockIdx.x < 25) zero_region[blockIdx.x * 256 + t] = 0.f;  // 6400 >= 6145
    int gw = blockIdx.x * 4 + wv;            // 0..2047
    int b = gw >> 8, d = gw & 255;
    __shared__ int cnt[4];
    __shared__ float s_alen;
    unsigned long long mb = __ballot(bidx[b * D_ + wv * 64 + lane] > 0);
    if (lane == 0) cnt[wv] = __popcll(mb);
    if (wv == 0) {
        unsigned long long ma = __ballot(aidx[b * Q_ + lane] > 0);
        if (lane == 0) s_alen = (float)__popcll(ma);
    }
    __syncthreads();
    float blen = (float)(cnt[0] + cnt[1] + cnt[2] + cnt[3]);
    int idx = bidx[b * D_ + d];
    const float4* row4 = (const float4*)(feats + (size_t)(b * S_ + idx) * H_);
    const float4* q0 = (const float4*)(qbar_part + (size_t)b * H_);
    const float4* q1 = (const float4*)(qbar_part + (size_t)(B_ + b) * H_);
    float dqf = 0.f;
#pragma unroll
    for (int k = 0; k < 3; ++k) {
        float4 v  = row4[lane + k * 64];
        float4 qa = q0[lane + k * 64];
        float4 qb = q1[lane + k * 64];
        dqf += v.x * (qa.x + qb.x) + v.y * (qa.y + qb.y)
             + v.z * (qa.z + qb.z) + v.w * (qa.w + qb.w);
    }
    for (int off = 32; off; off >>= 1) dqf += __shfl_xor(dqf, off, 64);
    if (lane == 0)
        w[b * D_ + d] = dqf * invd[b * D_ + d] / (s_alen * blen);
}

// ============================================================================
// K3: 96 blocks x 256 threads — qbd chunk + partial GEMV (atomicAdd hidden);
//     last finished block computes relu+logits (counter epilogue, as R4).
// ============================================================================
__global__ __launch_bounds__(256) void k_docsum_mlp(
        const float* __restrict__ feats,
        const int* __restrict__ aidx,
        const int* __restrict__ bidx,
        const float* __restrict__ W1,
        const float* __restrict__ b1,
        const float* __restrict__ W2,
        const float* __restrict__ b2,
        float* __restrict__ ws,
        float* __restrict__ out) {
    const float* qa_part = ws + WS_QAP;
    const float* w       = ws + WS_W;
    float* hidden        = ws + WS_HIDDEN;
    int* counter         = (int*)(ws + WS_CNT);
    const int b = blockIdx.x / 12, hc = blockIdx.x % 12;
    const int t = threadIdx.x, wv = t >> 6, lane = t & 63;
    __shared__ float s_w[D_];
    __shared__ int   s_i[D_];
    __shared__ float s_k[128];        // [0:64]=qa chunk, [64:128]=qbd chunk
    __shared__ float red[4][64];
    __shared__ float s_alen;
    __shared__ int   s_flag;
    s_w[t] = w[b * D_ + t];
    s_i[t] = bidx[b * D_ + t];
    if (wv == 0) {
        unsigned long long ma = __ballot(aidx[b * Q_ + lane] > 0);
        if (lane == 0) s_alen = (float)__popcll(ma);
    }
    __syncthreads();
    if (t < 64) {
        s_k[t] = (qa_part[(size_t)b * H_ + hc * 64 + t]
                + qa_part[(size_t)(B_ + b) * H_ + hc * 64 + t]) / s_alen;
    }
    int hh = hc * 64 + lane;
    float acc = 0.f;
#pragma unroll 8
    for (int d = wv * 64; d < wv * 64 + 64; ++d)
        acc += s_w[d] * feats[(size_t)(b * S_ + s_i[d]) * H_ + hh];
    red[wv][lane] = acc;
    __syncthreads();
    if (t < 64) s_k[64 + t] = red[0][t] + red[1][t] + red[2][t] + red[3][t];
    __syncthreads();
    // partial GEMV: k rows {hc*64..+64} (qa) and {768+hc*64..+64} (qbd)
    const float* Wtop = W1 + (size_t)(hc * 64) * H_;
    const float* Wbot = W1 + (size_t)(H_ + hc * 64) * H_;
    float h0 = 0.f, h1 = 0.f, h2 = 0.f;
#pragma unroll 4
    for (int i = 0; i < 64; ++i) {
        float ka = s_k[i], kb = s_k[64 + i];
        const float* r1 = Wtop + (size_t)i * H_;
        const float* r2 = Wbot + (size_t)i * H_;
        h0 += ka * r1[t]       + kb * r2[t];
        h1 += ka * r1[t + 256] + kb * r2[t + 256];
        h2 += ka * r1[t + 512] + kb * r2[t + 512];
    }
    atomicAdd(&hidden[b * H_ + t],       h0);
    atomicAdd(&hidden[b * H_ + t + 256], h1);
    atomicAdd(&hidden[b * H_ + t + 512], h2);
    __threadfence();
    __syncthreads();
    if (t == 0) {
        int old = atomicAdd(counter, 1);
        s_flag = (old == 95);
    }
    __syncthreads();
    if (s_flag) {
        __threadfence();
        for (int bb = wv * 2; bb < wv * 2 + 2; ++bb) {
            float a0 = 0.f, a1 = 0.f;
#pragma unroll
            for (int k = 0; k < 12; ++k) {
                int h = lane + k * 64;
                float hv = __hip_atomic_load(&hidden[bb * H_ + h],
                                             __ATOMIC_RELAXED,
                                             __HIP_MEMORY_SCOPE_AGENT);
                float v = fmaxf(hv + b1[h], 0.f);
                a0 += v * W2[h * 2 + 0];
                a1 += v * W2[h * 2 + 1];
            }
            for (int off = 32; off; off >>= 1) {
                a0 += __shfl_xor(a0, off, 64);
                a1 += __shfl_xor(a1, off, 64);
            }
            if (lane == 0) {
                out[bb * 2 + 0] = a0 + b2[0];
                out[bb * 2 + 1] = a1 + b2[1];
            }
        }
    }
}

extern "C" void kernel_launch(void* const* d_in, const int* in_sizes, int n_in,
                              void* d_out, int out_size, void* d_ws, size_t ws_size,
                              hipStream_t stream) {
    const float* feats = (const float*)d_in[0];
    const int*   aidx  = (const int*)d_in[1];
    const int*   bidx  = (const int*)d_in[2];
    const float* W1    = (const float*)d_in[3];
    const float* b1    = (const float*)d_in[4];
    const float* W2    = (const float*)d_in[5];
    const float* b2    = (const float*)d_in[6];
    float* out = (float*)d_out;
    float* ws = (float*)d_ws;

    k_pre<<<256, 512, 0, stream>>>(feats, aidx, bidx, ws);
    k_docw<<<512, 256, 0, stream>>>(feats, aidx, bidx, ws);
    k_docsum_mlp<<<96, 256, 0, stream>>>(feats, aidx, bidx, W1, b1, W2, b2, ws, out);
}

// Round 7
// 101.935 us; speedup vs baseline: 1.3254x; 1.0098x over previous
//
#include <hip/hip_runtime.h>
#include <hip/hip_bf16.h>

// Problem constants (B,S,H,Q,D,C) = (8,512,768,64,256,2)
#define B_ 8
#define S_ 512
#define H_ 768
#define Q_ 64
#define D_ 256
#define EPSF 1e-8f

// ws layout (floats)
#define WS_QBARP  0                           // [8][B][H] = 49152
#define WS_QAP    (8 * B_ * H_)               // [8][B][H] = 49152
#define WS_W      (16 * B_ * H_)              // [B*D] = 2048
#define WS_HIDDEN (16 * B_ * H_ + B_ * D_)    // [B*H] = 6144
#define WS_CNT    (WS_HIDDEN + B_ * H_)       // counter + pad

// ============================================================================
// K1: 64 blocks x 512 threads; block = (b, qg) owns 8 q-rows.
//   Phase 1: wave wv computes the (masked) inverse norm of its row.
//   Phase 2: column pass — thread t accumulates cols t (and 512+t for t<256)
//            over the 8 rows -> qbar_part/qa_part[qg][b][col]. Coalesced.
// ============================================================================
__global__ __launch_bounds__(512) void k_qnorm(
        const float* __restrict__ feats,
        const int* __restrict__ aidx,
        float* __restrict__ ws) {
    float* qbar_part = ws + WS_QBARP;
    float* qa_part   = ws + WS_QAP;
    const int b = blockIdx.x >> 3, qg = blockIdx.x & 7;
    const int t = threadIdx.x, wv = t >> 6, lane = t & 63;
    __shared__ int   s_ai[8];
    __shared__ float s_inv[8], s_m[8];
    if (t < 8) s_ai[t] = aidx[b * Q_ + qg * 8 + t];
    __syncthreads();
    {
        int idx = s_ai[wv];
        const float4* row4 = (const float4*)(feats + (size_t)(b * S_ + idx) * H_);
        float4 v0 = row4[lane], v1 = row4[lane + 64], v2 = row4[lane + 128];
        float ss = v0.x*v0.x + v0.y*v0.y + v0.z*v0.z + v0.w*v0.w
                 + v1.x*v1.x + v1.y*v1.y + v1.z*v1.z + v1.w*v1.w
                 + v2.x*v2.x + v2.y*v2.y + v2.z*v2.z + v2.w*v2.w;
        for (int off = 32; off; off >>= 1) ss += __shfl_xor(ss, off, 64);
        if (lane == 0) {
            float inv = 1.f / fmaxf(sqrtf(ss), EPSF);
            s_inv[wv] = (idx > 0) ? inv : 0.f;
            s_m[wv]   = (idx > 0) ? 1.f : 0.f;
        }
    }
    __syncthreads();
    float pb0 = 0.f, pa0 = 0.f, pb1 = 0.f, pa1 = 0.f;
#pragma unroll
    for (int j = 0; j < 8; ++j) {
        const float* row = feats + (size_t)(b * S_ + s_ai[j]) * H_;
        float iv = s_inv[j], mv = s_m[j];
        float f0 = row[t];
        pb0 += f0 * iv; pa0 += f0 * mv;
        if (t < 256) {
            float f1 = row[512 + t];
            pb1 += f1 * iv; pa1 += f1 * mv;
        }
    }
    size_t base = (size_t)(qg * B_ + b) * H_;
    qbar_part[base + t] = pb0;
    qa_part[base + t]   = pa0;
    if (t < 256) {
        qbar_part[base + 512 + t] = pb1;
        qa_part[base + 512 + t]   = pa1;
    }
}

// ============================================================================
// K2: 512 blocks x 256 threads — block covers 4 docs of one batch.
//   Sum the 8 qbar parts into LDS, then dual-dot (q.f and f.f) in ONE row
//   pass: w[b,d] = mask * (qbar.f_d) / (||f_d|| * alen * blen).
//   Blocks 0..24 also zero hidden+counter (stream-ordered before K3).
// ============================================================================
__global__ __launch_bounds__(256) void k_docw(
        const float* __restrict__ feats,
        const int* __restrict__ aidx,
        const int* __restrict__ bidx,
        float* __restrict__ ws) {
    const float* qbar_part = ws + WS_QBARP;
    float* w           = ws + WS_W;
    float* zero_region = ws + WS_HIDDEN;
    const int t = threadIdx.x, wv = t >> 6, lane = t & 63;
    if (blockIdx.x < 25) zero_region[blockIdx.x * 256 + t] = 0.f;  // 6400 >= 6145
    const int gw = blockIdx.x * 4 + wv;      // 0..2047
    const int b = gw >> 8, d = gw & 255;     // b uniform per block (64 blocks/batch)
    __shared__ __align__(16) float s_qbar[H_];
    __shared__ int cnt[4];
    __shared__ float s_alen;
    // sum 8 parts -> s_qbar (coalesced, L2-hot)
#pragma unroll
    for (int c = 0; c < 3; ++c) {
        int col = c * 256 + t;
        float s = 0.f;
#pragma unroll
        for (int p = 0; p < 8; ++p)
            s += qbar_part[(size_t)(p * B_ + b) * H_ + col];
        s_qbar[col] = s;
    }
    unsigned long long mb = __ballot(bidx[b * D_ + wv * 64 + lane] > 0);
    if (lane == 0) cnt[wv] = __popcll(mb);
    if (wv == 0) {
        unsigned long long ma = __ballot(aidx[b * Q_ + lane] > 0);
        if (lane == 0) s_alen = (float)__popcll(ma);
    }
    __syncthreads();
    float blen = (float)(cnt[0] + cnt[1] + cnt[2] + cnt[3]);
    int idx = bidx[b * D_ + d];
    const float4* row4 = (const float4*)(feats + (size_t)(b * S_ + idx) * H_);
    const float4* q4 = (const float4*)s_qbar;
    float dqf = 0.f, dff = 0.f;
#pragma unroll
    for (int k = 0; k < 3; ++k) {
        float4 v = row4[lane + k * 64];
        float4 q = q4[lane + k * 64];
        dqf += v.x*q.x + v.y*q.y + v.z*q.z + v.w*q.w;
        dff += v.x*v.x + v.y*v.y + v.z*v.z + v.w*v.w;
    }
    for (int off = 32; off; off >>= 1) {
        dqf += __shfl_xor(dqf, off, 64);
        dff += __shfl_xor(dff, off, 64);
    }
    if (lane == 0) {
        float invd = 1.f / fmaxf(sqrtf(dff), EPSF);
        float scale = 1.f / (s_alen * blen);
        w[b * D_ + d] = (idx > 0) ? dqf * invd * scale : 0.f;
    }
}

// ============================================================================
// K3: 96 blocks x 256 threads — qbd chunk + partial GEMV (atomicAdd hidden);
//     last-done block computes relu+logits (counter epilogue; proven R4/R6).
// ============================================================================
__global__ __launch_bounds__(256) void k_docsum_mlp(
        const float* __restrict__ feats,
        const int* __restrict__ aidx,
        const int* __restrict__ bidx,
        const float* __restrict__ W1,
        const float* __restrict__ b1,
        const float* __restrict__ W2,
        const float* __restrict__ b2,
        float* __restrict__ ws,
        float* __restrict__ out) {
    const float* qa_part = ws + WS_QAP;
    const float* w       = ws + WS_W;
    float* hidden        = ws + WS_HIDDEN;
    int* counter         = (int*)(ws + WS_CNT);
    const int b = blockIdx.x / 12, hc = blockIdx.x % 12;
    const int t = threadIdx.x, wv = t >> 6, lane = t & 63;
    __shared__ float s_w[D_];
    __shared__ int   s_i[D_];
    __shared__ float s_k[128];        // [0:64]=qa chunk, [64:128]=qbd chunk
    __shared__ float red[4][64];
    __shared__ float s_alen;
    __shared__ int   s_flag;
    s_w[t] = w[b * D_ + t];
    s_i[t] = bidx[b * D_ + t];
    if (wv == 0) {
        unsigned long long ma = __ballot(aidx[b * Q_ + lane] > 0);
        if (lane == 0) s_alen = (float)__popcll(ma);
    }
    __syncthreads();
    if (t < 64) {
        float s = 0.f;
#pragma unroll
        for (int p = 0; p < 8; ++p)
            s += qa_part[(size_t)(p * B_ + b) * H_ + hc * 64 + t];
        s_k[t] = s / s_alen;
    }
    int hh = hc * 64 + lane;
    float acc = 0.f;
#pragma unroll 8
    for (int d = wv * 64; d < wv * 64 + 64; ++d)
        acc += s_w[d] * feats[(size_t)(b * S_ + s_i[d]) * H_ + hh];
    red[wv][lane] = acc;
    __syncthreads();
    if (t < 64) s_k[64 + t] = red[0][t] + red[1][t] + red[2][t] + red[3][t];
    __syncthreads();
    // partial GEMV: k rows {hc*64..+64} (qa) and {768+hc*64..+64} (qbd)
    const float* Wtop = W1 + (size_t)(hc * 64) * H_;
    const float* Wbot = W1 + (size_t)(H_ + hc * 64) * H_;
    float h0 = 0.f, h1 = 0.f, h2 = 0.f;
#pragma unroll 4
    for (int i = 0; i < 64; ++i) {
        float ka = s_k[i], kb = s_k[64 + i];
        const float* r1 = Wtop + (size_t)i * H_;
        const float* r2 = Wbot + (size_t)i * H_;
        h0 += ka * r1[t]       + kb * r2[t];
        h1 += ka * r1[t + 256] + kb * r2[t + 256];
        h2 += ka * r1[t + 512] + kb * r2[t + 512];
    }
    atomicAdd(&hidden[b * H_ + t],       h0);
    atomicAdd(&hidden[b * H_ + t + 256], h1);
    atomicAdd(&hidden[b * H_ + t + 512], h2);
    __threadfence();
    __syncthreads();
    if (t == 0) {
        int old = atomicAdd(counter, 1);
        s_flag = (old == 95);
    }
    __syncthreads();
    if (s_flag) {
        __threadfence();
        for (int bb = wv * 2; bb < wv * 2 + 2; ++bb) {
            float a0 = 0.f, a1 = 0.f;
#pragma unroll
            for (int k = 0; k < 12; ++k) {
                int h = lane + k * 64;
                float hv = __hip_atomic_load(&hidden[bb * H_ + h],
                                             __ATOMIC_RELAXED,
                                             __HIP_MEMORY_SCOPE_AGENT);
                float v = fmaxf(hv + b1[h], 0.f);
                a0 += v * W2[h * 2 + 0];
                a1 += v * W2[h * 2 + 1];
            }
            for (int off = 32; off; off >>= 1) {
                a0 += __shfl_xor(a0, off, 64);
                a1 += __shfl_xor(a1, off, 64);
            }
            if (lane == 0) {
                out[bb * 2 + 0] = a0 + b2[0];
                out[bb * 2 + 1] = a1 + b2[1];
            }
        }
    }
}

extern "C" void kernel_launch(void* const* d_in, const int* in_sizes, int n_in,
                              void* d_out, int out_size, void* d_ws, size_t ws_size,
                              hipStream_t stream) {
    const float* feats = (const float*)d_in[0];
    const int*   aidx  = (const int*)d_in[1];
    const int*   bidx  = (const int*)d_in[2];
    const float* W1    = (const float*)d_in[3];
    const float* b1    = (const float*)d_in[4];
    const float* W2    = (const float*)d_in[5];
    const float* b2    = (const float*)d_in[6];
    float* out = (float*)d_out;
    float* ws = (float*)d_ws;

    k_qnorm<<<64, 512, 0, stream>>>(feats, aidx, ws);
    k_docw<<<512, 256, 0, stream>>>(feats, aidx, bidx, ws);
    k_docsum_mlp<<<96, 256, 0, stream>>>(feats, aidx, bidx, W1, b1, W2, b2, ws, out);
}